// Round 1
// baseline (352.385 us; speedup 1.0000x reference)
//
#include <hip/hip_runtime.h>
#include <stdint.h>

#define IN_F 4096
#define OUT_F 4096
#define M_TOT 8192
#define LORA_SCALE 4.0f   // ALPHA / RANK = 32 / 8

typedef unsigned short u16;
typedef __attribute__((ext_vector_type(8))) short bf16x8;   // 8 bf16 = 4 VGPRs
typedef __attribute__((ext_vector_type(4))) float f32x4;

__device__ __forceinline__ u16 f2bf(float f) {
  union { float f; unsigned u; } v; v.f = f;
  unsigned r = v.u + 0x7FFFu + ((v.u >> 16) & 1u);  // round-to-nearest-even
  return (u16)(r >> 16);
}

__device__ __forceinline__ void gload_lds16(const void* g, void* l) {
  __builtin_amdgcn_global_load_lds(
      (const __attribute__((address_space(1))) void*)g,
      (__attribute__((address_space(3))) void*)l, 16, 0, 0);
}

// ---------------------------------------------------------------------------
// Kernel 1: Wb[o][i] = bf16( W[o][i] + 4 * sum_r a[o][r]*b[r][i] )   [N][K]
// 4 elements / thread. a-row is wave-uniform (scalar load); b rows L2-resident.
__global__ void merge_weight(const float* __restrict__ W,
                             const float* __restrict__ A,
                             const float* __restrict__ B,
                             u16* __restrict__ Wb) {
  int idx = blockIdx.x * blockDim.x + threadIdx.x;   // OUT_F * IN_F / 4 threads
  int o  = idx >> 10;                                // IN_F/4 = 1024 threads per row
  int i0 = (idx & 1023) << 2;
  const float4 w = *(const float4*)(W + (size_t)o * IN_F + i0);
  float a0 = w.x, a1 = w.y, a2 = w.z, a3 = w.w;
#pragma unroll
  for (int r = 0; r < 8; ++r) {
    float ar = A[o * 8 + r] * LORA_SCALE;
    const float4 bv = *(const float4*)(B + (size_t)r * IN_F + i0);
    a0 += ar * bv.x; a1 += ar * bv.y; a2 += ar * bv.z; a3 += ar * bv.w;
  }
  uint2 pk;
  pk.x = (unsigned)f2bf(a0) | ((unsigned)f2bf(a1) << 16);
  pk.y = (unsigned)f2bf(a2) | ((unsigned)f2bf(a3) << 16);
  *(uint2*)(Wb + (size_t)o * IN_F + i0) = pk;
}

// ---------------------------------------------------------------------------
// Kernel 2: Xb = bf16(x), 8 elements / thread (2x float4 in, uint4 out)
__global__ void convert_x(const float* __restrict__ X, u16* __restrict__ Xb) {
  size_t base = ((size_t)blockIdx.x * blockDim.x + threadIdx.x) * 8;
  float4 v0 = *(const float4*)(X + base);
  float4 v1 = *(const float4*)(X + base + 4);
  uint4 pk;
  pk.x = (unsigned)f2bf(v0.x) | ((unsigned)f2bf(v0.y) << 16);
  pk.y = (unsigned)f2bf(v0.z) | ((unsigned)f2bf(v0.w) << 16);
  pk.z = (unsigned)f2bf(v1.x) | ((unsigned)f2bf(v1.y) << 16);
  pk.w = (unsigned)f2bf(v1.z) | ((unsigned)f2bf(v1.w) << 16);
  *(uint4*)(Xb + base) = pk;
}

// ---------------------------------------------------------------------------
// Kernel 3: out[m][n] = sum_k Xb[m][k]*Wb[n][k] + bias[n]
// 128x128 tile, BK=64, 4 waves (2x2), 16x16x32 bf16 MFMA.
// Staging: global_load_lds width 16, linear LDS dest, PRE-SWIZZLED global src
// (chunk ^= row&7, 16B chunks within a 128B row) so ds_read_b128 fragment
// reads are 2-way-conflict-free (free on CDNA4).
__global__ __launch_bounds__(256) void gemm_bias(const u16* __restrict__ Xb,
                                                 const u16* __restrict__ Wb,
                                                 const float* __restrict__ bias,
                                                 float* __restrict__ out) {
  __shared__ __align__(16) u16 ldsA[128 * 64];   // 16 KB, rows of 64 bf16 (128 B)
  __shared__ __align__(16) u16 ldsB[128 * 64];   // 16 KB

  const int tid  = threadIdx.x;
  const int wid  = tid >> 6;
  const int lane = tid & 63;
  const int nt = blockIdx.x & 31;               // 32 N-tiles
  const int mt = blockIdx.x >> 5;               // 64 M-tiles
  const int m0 = mt * 128, n0 = nt * 128;
  const int wr = wid >> 1, wc = wid & 1;        // 2x2 waves, 64x64 each
  const int lr = lane & 15;                     // fragment row/col
  const int kg = lane >> 4;                     // k-group (0..3)

  // staging geometry: per round j (0..3), wave covers 8 rows x 64 bf16 = 1 KB
  const int srow   = wid * 8 + (lane >> 3);           // + j*32
  const int schunk = (lane & 7) ^ (srow & 7);         // logical 16B chunk to fetch
  const u16* aSrc = Xb + (size_t)(m0 + srow) * IN_F + schunk * 8;
  const u16* bSrc = Wb + (size_t)(n0 + srow) * IN_F + schunk * 8;

  f32x4 acc[4][4] = {};

  for (int kt = 0; kt < IN_F; kt += 64) {
    __syncthreads();                       // all waves done reading prev tile
#pragma unroll
    for (int j = 0; j < 4; ++j) {
      gload_lds16(aSrc + (size_t)(j * 32) * IN_F + kt, &ldsA[j * 2048 + wid * 512]);
      gload_lds16(bSrc + (size_t)(j * 32) * IN_F + kt, &ldsB[j * 2048 + wid * 512]);
    }
    __syncthreads();                       // drains vmcnt before compute

#pragma unroll
    for (int s = 0; s < 2; ++s) {          // two K=32 slices of BK=64
      bf16x8 af[4], bfr[4];
#pragma unroll
      for (int m = 0; m < 4; ++m) {
        int r = wr * 64 + m * 16 + lr;
        int c = (s * 4 + kg) ^ (r & 7);
        af[m] = *(const bf16x8*)&ldsA[r * 64 + c * 8];
      }
#pragma unroll
      for (int n = 0; n < 4; ++n) {
        int r = wc * 64 + n * 16 + lr;
        int c = (s * 4 + kg) ^ (r & 7);
        bfr[n] = *(const bf16x8*)&ldsB[r * 64 + c * 8];
      }
#pragma unroll
      for (int m = 0; m < 4; ++m)
#pragma unroll
        for (int n = 0; n < 4; ++n)
          acc[m][n] = __builtin_amdgcn_mfma_f32_16x16x32_bf16(af[m], bfr[n], acc[m][n], 0, 0, 0);
    }
  }

  // epilogue: C/D layout col = lane&15, row = (lane>>4)*4 + reg
  float bv[4];
#pragma unroll
  for (int n = 0; n < 4; ++n) bv[n] = bias[n0 + wc * 64 + n * 16 + lr];
  const int rbase = m0 + wr * 64 + kg * 4;
#pragma unroll
  for (int m = 0; m < 4; ++m)
#pragma unroll
    for (int n = 0; n < 4; ++n) {
      int col = n0 + wc * 64 + n * 16 + lr;
#pragma unroll
      for (int r = 0; r < 4; ++r)
        out[(size_t)(rbase + m * 16 + r) * OUT_F + col] = acc[m][n][r] + bv[n];
    }
}

// ---------------------------------------------------------------------------
// Fallback path (only if ws_size < 100.7 MB): exact fp32, slow but correct.
__global__ void lora_t(const float* __restrict__ x, const float* __restrict__ B,
                       float* __restrict__ t) {
  int m = blockIdx.x;
  int tid = threadIdx.x, lane = tid & 63;
  float p[8] = {0, 0, 0, 0, 0, 0, 0, 0};
  for (int k = tid; k < IN_F; k += 256) {
    float xv = x[(size_t)m * IN_F + k];
#pragma unroll
    for (int r = 0; r < 8; ++r) p[r] += xv * B[r * IN_F + k];
  }
#pragma unroll
  for (int r = 0; r < 8; ++r) {
    float v = p[r];
    for (int off = 32; off; off >>= 1) v += __shfl_down(v, off);
    if (lane == 0) atomicAdd(&t[m * 8 + r], v);
  }
}

__global__ void fb_gemm(const float* __restrict__ x, const float* __restrict__ W,
                        const float* __restrict__ A, const float* __restrict__ bias,
                        const float* __restrict__ t, float* __restrict__ out) {
  __shared__ float sx[64][17];
  __shared__ float sw[64][17];
  int tx = threadIdx.x, ty = threadIdx.y;
  int tid = ty * 16 + tx;
  int m0 = blockIdx.y * 64, n0 = blockIdx.x * 64;
  float acc[4][4] = {};
  for (int kt = 0; kt < IN_F; kt += 16) {
    __syncthreads();
#pragma unroll
    for (int q = 0; q < 4; ++q) {
      int idx = q * 256 + tid;
      int r = idx >> 4, c = idx & 15;
      sx[r][c] = x[(size_t)(m0 + r) * IN_F + kt + c];
      sw[r][c] = W[(size_t)(n0 + r) * IN_F + kt + c];
    }
    __syncthreads();
#pragma unroll
    for (int k = 0; k < 16; ++k) {
      float xv[4], wv[4];
#pragma unroll
      for (int i = 0; i < 4; ++i) xv[i] = sx[ty * 4 + i][k];
#pragma unroll
      for (int j = 0; j < 4; ++j) wv[j] = sw[tx * 4 + j][k];
#pragma unroll
      for (int i = 0; i < 4; ++i)
#pragma unroll
        for (int j = 0; j < 4; ++j) acc[i][j] += xv[i] * wv[j];
    }
  }
#pragma unroll
  for (int i = 0; i < 4; ++i) {
    int m = m0 + ty * 4 + i;
    float tv[8];
#pragma unroll
    for (int r = 0; r < 8; ++r) tv[r] = t[m * 8 + r];
#pragma unroll
    for (int j = 0; j < 4; ++j) {
      int o = n0 + tx * 4 + j;
      float lora = 0.f;
#pragma unroll
      for (int r = 0; r < 8; ++r) lora += tv[r] * A[o * 8 + r];
      out[(size_t)m * OUT_F + o] = acc[i][j] + bias[o] + LORA_SCALE * lora;
    }
  }
}

// ---------------------------------------------------------------------------
extern "C" void kernel_launch(void* const* d_in, const int* in_sizes, int n_in,
                              void* d_out, int out_size, void* d_ws, size_t ws_size,
                              hipStream_t stream) {
  const float* x    = (const float*)d_in[0];
  const float* W    = (const float*)d_in[1];
  const float* A    = (const float*)d_in[2];
  const float* B    = (const float*)d_in[3];
  const float* bias = (const float*)d_in[4];
  float* out = (float*)d_out;

  const size_t xb_elems = (size_t)M_TOT * IN_F;   // 33.5M bf16 = 67.1 MB
  const size_t wb_elems = (size_t)OUT_F * IN_F;   // 16.8M bf16 = 33.5 MB
  const size_t need = (xb_elems + wb_elems) * sizeof(u16);

  if (ws_size >= need) {
    u16* Xb = (u16*)d_ws;
    u16* Wb = Xb + xb_elems;
    merge_weight<<<(OUT_F * IN_F / 4) / 256, 256, 0, stream>>>(W, A, B, Wb);
    convert_x<<<(M_TOT * IN_F / 8) / 256, 256, 0, stream>>>(x, Xb);
    gemm_bias<<<(M_TOT / 128) * (OUT_F / 128), 256, 0, stream>>>(Xb, Wb, bias, out);
  } else {
    // exact fp32 fallback (ws only needs 256 KB for t = x @ b^T)
    float* t = (float*)d_ws;
    hipMemsetAsync(t, 0, (size_t)M_TOT * 8 * sizeof(float), stream);
    lora_t<<<M_TOT, 256, 0, stream>>>(x, B, t);
    fb_gemm<<<dim3(OUT_F / 64, M_TOT / 64), dim3(16, 16), 0, stream>>>(x, W, A, bias, t, out);
  }
}

// Round 2
// 299.706 us; speedup vs baseline: 1.1758x; 1.1758x over previous
//
#include <hip/hip_runtime.h>
#include <stdint.h>

#define IN_F 4096
#define OUT_F 4096
#define M_TOT 8192
#define LORA_SCALE 4.0f   // ALPHA / RANK = 32 / 8

typedef unsigned short u16;
typedef __attribute__((ext_vector_type(8))) short bf16x8;   // 8 bf16 = 4 VGPRs
typedef __attribute__((ext_vector_type(4))) float f32x4;

__device__ __forceinline__ u16 f2bf(float f) {
  union { float f; unsigned u; } v; v.f = f;
  unsigned r = v.u + 0x7FFFu + ((v.u >> 16) & 1u);  // round-to-nearest-even
  return (u16)(r >> 16);
}

__device__ __forceinline__ void gload_lds16(const void* g, void* l) {
  __builtin_amdgcn_global_load_lds(
      (const __attribute__((address_space(1))) void*)g,
      (__attribute__((address_space(3))) void*)l, 16, 0, 0);
}

// ---------------------------------------------------------------------------
// Kernel 1: Wb[o][i] = bf16( W[o][i] + 4 * sum_r a[o][r]*b[r][i] )   [N][K]
__global__ void merge_weight(const float* __restrict__ W,
                             const float* __restrict__ A,
                             const float* __restrict__ B,
                             u16* __restrict__ Wb) {
  int idx = blockIdx.x * blockDim.x + threadIdx.x;
  int o  = idx >> 10;
  int i0 = (idx & 1023) << 2;
  const float4 w = *(const float4*)(W + (size_t)o * IN_F + i0);
  float a0 = w.x, a1 = w.y, a2 = w.z, a3 = w.w;
#pragma unroll
  for (int r = 0; r < 8; ++r) {
    float ar = A[o * 8 + r] * LORA_SCALE;
    const float4 bv = *(const float4*)(B + (size_t)r * IN_F + i0);
    a0 += ar * bv.x; a1 += ar * bv.y; a2 += ar * bv.z; a3 += ar * bv.w;
  }
  uint2 pk;
  pk.x = (unsigned)f2bf(a0) | ((unsigned)f2bf(a1) << 16);
  pk.y = (unsigned)f2bf(a2) | ((unsigned)f2bf(a3) << 16);
  *(uint2*)(Wb + (size_t)o * IN_F + i0) = pk;
}

// ---------------------------------------------------------------------------
// Kernel 2: Xb = bf16(x), 8 elements / thread
__global__ void convert_x(const float* __restrict__ X, u16* __restrict__ Xb) {
  size_t base = ((size_t)blockIdx.x * blockDim.x + threadIdx.x) * 8;
  float4 v0 = *(const float4*)(X + base);
  float4 v1 = *(const float4*)(X + base + 4);
  uint4 pk;
  pk.x = (unsigned)f2bf(v0.x) | ((unsigned)f2bf(v0.y) << 16);
  pk.y = (unsigned)f2bf(v0.z) | ((unsigned)f2bf(v0.w) << 16);
  pk.z = (unsigned)f2bf(v1.x) | ((unsigned)f2bf(v1.y) << 16);
  pk.w = (unsigned)f2bf(v1.z) | ((unsigned)f2bf(v1.w) << 16);
  *(uint4*)(Xb + base) = pk;
}

// ---------------------------------------------------------------------------
// Kernel 3 (primary): 256x256 tile, BK=64, 8 waves (2Mx4N), 8-phase schedule
// with counted vmcnt (T3+T4), XOR-swizzled LDS (T2), setprio (T5), XCD swizzle
// (T1). LDS = 128 KB dynamic, double-buffered.
//
// Stage order per K-tile: B.h0, B.h1, A.h0, A.h1 (2 gloads each).
// During tile t's 4 phases we stage: (t+1).A0, (t+1).A1, (t+2).B0, (t+2).B1.
// Safe because: B of a buffer is reg-loaded entirely in phase 0 of its tile
// (free for overwrite from phase 2 on); A is read through phase 3 and only
// overwritten by tiles t+2 staged during tile t+1's phases. vmcnt(4) at each
// tile's phase 3 guarantees the next tile fully landed; 2 half-tiles stay in
// flight (never drains to 0 in the main loop).

#define ABASE(b) ((b) * 32768)
#define BBASE(b) ((b) * 32768 + 16384)

#define STAGE_A(b, h, kt) do { \
  gload_lds16(aG + (size_t)((h) * 128) * IN_F + (kt),      lds + ABASE(b) + ((h) * 128) * 64      + tid * 8); \
  gload_lds16(aG + (size_t)((h) * 128 + 64) * IN_F + (kt), lds + ABASE(b) + ((h) * 128 + 64) * 64 + tid * 8); \
} while (0)

#define STAGE_B(b, h, kt) do { \
  gload_lds16(bG + (size_t)((h) * 128) * IN_F + (kt),      lds + BBASE(b) + ((h) * 128) * 64      + tid * 8); \
  gload_lds16(bG + (size_t)((h) * 128 + 64) * IN_F + (kt), lds + BBASE(b) + ((h) * 128 + 64) * 64 + tid * 8); \
} while (0)

#define WAIT4 asm volatile("s_waitcnt vmcnt(4)")
#define WAIT0 asm volatile("s_waitcnt vmcnt(0)")

#define PHASE(b, p, STAGE_STMT, WAIT_STMT) do { \
  if ((p) == 0) { \
    _Pragma("unroll") \
    for (int n = 0; n < 4; ++n) { \
      Bf0[n] = *(const bf16x8*)(lds + BBASE(b) + (rB + n * 16) * 64 + ck0); \
      Bf1[n] = *(const bf16x8*)(lds + BBASE(b) + (rB + n * 16) * 64 + ck1); \
    } \
  } \
  bf16x8 a00 = *(const bf16x8*)(lds + ABASE(b) + (rA + (2 * (p)) * 16) * 64 + ck0); \
  bf16x8 a01 = *(const bf16x8*)(lds + ABASE(b) + (rA + (2 * (p)) * 16) * 64 + ck1); \
  bf16x8 a10 = *(const bf16x8*)(lds + ABASE(b) + (rA + (2 * (p) + 1) * 16) * 64 + ck0); \
  bf16x8 a11 = *(const bf16x8*)(lds + ABASE(b) + (rA + (2 * (p) + 1) * 16) * 64 + ck1); \
  STAGE_STMT; \
  __builtin_amdgcn_s_barrier(); \
  asm volatile("s_waitcnt lgkmcnt(0)"); \
  __builtin_amdgcn_s_setprio(1); \
  _Pragma("unroll") \
  for (int n = 0; n < 4; ++n) { \
    acc[2 * (p)][n]     = __builtin_amdgcn_mfma_f32_16x16x32_bf16(a00, Bf0[n], acc[2 * (p)][n], 0, 0, 0); \
    acc[2 * (p) + 1][n] = __builtin_amdgcn_mfma_f32_16x16x32_bf16(a10, Bf0[n], acc[2 * (p) + 1][n], 0, 0, 0); \
  } \
  _Pragma("unroll") \
  for (int n = 0; n < 4; ++n) { \
    acc[2 * (p)][n]     = __builtin_amdgcn_mfma_f32_16x16x32_bf16(a01, Bf1[n], acc[2 * (p)][n], 0, 0, 0); \
    acc[2 * (p) + 1][n] = __builtin_amdgcn_mfma_f32_16x16x32_bf16(a11, Bf1[n], acc[2 * (p) + 1][n], 0, 0, 0); \
  } \
  __builtin_amdgcn_s_setprio(0); \
  WAIT_STMT; \
  __builtin_amdgcn_s_barrier(); \
} while (0)

__global__ __launch_bounds__(512, 2) void gemm8(const u16* __restrict__ Xb,
                                                const u16* __restrict__ Wb,
                                                const float* __restrict__ bias,
                                                float* __restrict__ out) {
  extern __shared__ u16 lds[];

  const int tid  = threadIdx.x;
  const int lane = tid & 63;
  const int wid  = tid >> 6;
  const int wr = wid >> 2, wc = wid & 3;       // 2x4 waves, 128x64 C each
  const int lr = lane & 15, kg = lane >> 4;

  // XCD-aware swizzle: nwg = 512, divisible by 8
  const int bid = blockIdx.x;
  const int swz = (bid & 7) * 64 + (bid >> 3);
  const int mt = swz >> 4, nt = swz & 15;       // 32 M-tiles x 16 N-tiles
  const int m0 = mt * 256, n0 = nt * 256;

  // staging: per half-tile (128 rows x 64 bf16), 2 gloads/thread.
  // LDS dest linear (lane*16); global source pre-swizzled chunk^(row&7).
  const int srow = tid >> 3;                                  // 0..63
  const int swc  = (tid & 7) ^ (srow & 7);
  const u16* aG = Xb + (size_t)(m0 + srow) * IN_F + swc * 8;
  const u16* bG = Wb + (size_t)(n0 + srow) * IN_F + swc * 8;

  // fragment read offsets (swizzled): row&7 == lane&7 for both A and B
  const int rA = wr * 128 + lr;
  const int rB = wc * 64 + lr;
  const int ck0 = ((kg) ^ (lane & 7)) * 8;       // k-slice 0
  const int ck1 = ((4 + kg) ^ (lane & 7)) * 8;   // k-slice 1

  f32x4 acc[8][4] = {};
  bf16x8 Bf0[4], Bf1[4];

  // prologue: tile0.{B0,B1,A0,A1}, tile1.{B0,B1}; wait tile0 landed (4 left)
  STAGE_B(0, 0, 0); STAGE_B(0, 1, 0);
  STAGE_A(0, 0, 0); STAGE_A(0, 1, 0);
  STAGE_B(1, 0, 64); STAGE_B(1, 1, 64);
  WAIT4;
  __builtin_amdgcn_s_barrier();

  for (int i = 0; i < 31; ++i) {
    const int kt1 = i * 128 + 64, kt2 = i * 128 + 128, kt3 = i * 128 + 192;
    // tile 2i (buffer 0)
    PHASE(0, 0, STAGE_A(1, 0, kt1), );
    PHASE(0, 1, STAGE_A(1, 1, kt1), );
    PHASE(0, 2, STAGE_B(0, 0, kt2), );
    PHASE(0, 3, STAGE_B(0, 1, kt2), WAIT4);
    // tile 2i+1 (buffer 1)
    PHASE(1, 0, STAGE_A(0, 0, kt2), );
    PHASE(1, 1, STAGE_A(0, 1, kt2), );
    PHASE(1, 2, STAGE_B(1, 0, kt3), );
    PHASE(1, 3, STAGE_B(1, 1, kt3), WAIT4);
  }
  // epilogue: tiles 62 (buf 0, kt=3968) and 63 (buf 1, kt=4032)
  PHASE(0, 0, STAGE_A(1, 0, 4032), );
  PHASE(0, 1, STAGE_A(1, 1, 4032), );
  PHASE(0, 2, , );
  PHASE(0, 3, , WAIT0);
  PHASE(1, 0, , );
  PHASE(1, 1, , );
  PHASE(1, 2, , );
  PHASE(1, 3, , );

  // C write + bias. C/D layout: col = lane&15, row = (lane>>4)*4 + reg
  float bv[4];
#pragma unroll
  for (int n = 0; n < 4; ++n) bv[n] = bias[n0 + wc * 64 + n * 16 + lr];
  const int rbase = m0 + wr * 128 + kg * 4;
#pragma unroll
  for (int m = 0; m < 8; ++m)
#pragma unroll
    for (int n = 0; n < 4; ++n) {
      int col = n0 + wc * 64 + n * 16 + lr;
#pragma unroll
      for (int r = 0; r < 4; ++r)
        out[(size_t)(rbase + m * 16 + r) * OUT_F + col] = acc[m][n][r] + bv[n];
    }
}

// ---------------------------------------------------------------------------
// Fallback GEMM (proven round-1 kernel): 128x128 tile, m97 structure, 859 TF.
__global__ __launch_bounds__(256) void gemm_bias(const u16* __restrict__ Xb,
                                                 const u16* __restrict__ Wb,
                                                 const float* __restrict__ bias,
                                                 float* __restrict__ out) {
  __shared__ __align__(16) u16 ldsA[128 * 64];
  __shared__ __align__(16) u16 ldsB[128 * 64];

  const int tid  = threadIdx.x;
  const int wid  = tid >> 6;
  const int lane = tid & 63;
  const int nt = blockIdx.x & 31;
  const int mt = blockIdx.x >> 5;
  const int m0 = mt * 128, n0 = nt * 128;
  const int wr = wid >> 1, wc = wid & 1;
  const int lr = lane & 15;
  const int kg = lane >> 4;

  const int srow   = wid * 8 + (lane >> 3);
  const int schunk = (lane & 7) ^ (srow & 7);
  const u16* aSrc = Xb + (size_t)(m0 + srow) * IN_F + schunk * 8;
  const u16* bSrc = Wb + (size_t)(n0 + srow) * IN_F + schunk * 8;

  f32x4 acc[4][4] = {};

  for (int kt = 0; kt < IN_F; kt += 64) {
    __syncthreads();
#pragma unroll
    for (int j = 0; j < 4; ++j) {
      gload_lds16(aSrc + (size_t)(j * 32) * IN_F + kt, &ldsA[j * 2048 + wid * 512]);
      gload_lds16(bSrc + (size_t)(j * 32) * IN_F + kt, &ldsB[j * 2048 + wid * 512]);
    }
    __syncthreads();

#pragma unroll
    for (int s = 0; s < 2; ++s) {
      bf16x8 af[4], bfr[4];
#pragma unroll
      for (int m = 0; m < 4; ++m) {
        int r = wr * 64 + m * 16 + lr;
        int c = (s * 4 + kg) ^ (r & 7);
        af[m] = *(const bf16x8*)&ldsA[r * 64 + c * 8];
      }
#pragma unroll
      for (int n = 0; n < 4; ++n) {
        int r = wc * 64 + n * 16 + lr;
        int c = (s * 4 + kg) ^ (r & 7);
        bfr[n] = *(const bf16x8*)&ldsB[r * 64 + c * 8];
      }
#pragma unroll
      for (int m = 0; m < 4; ++m)
#pragma unroll
        for (int n = 0; n < 4; ++n)
          acc[m][n] = __builtin_amdgcn_mfma_f32_16x16x32_bf16(af[m], bfr[n], acc[m][n], 0, 0, 0);
    }
  }

  float bv[4];
#pragma unroll
  for (int n = 0; n < 4; ++n) bv[n] = bias[n0 + wc * 64 + n * 16 + lr];
  const int rbase = m0 + wr * 64 + kg * 4;
#pragma unroll
  for (int m = 0; m < 4; ++m)
#pragma unroll
    for (int n = 0; n < 4; ++n) {
      int col = n0 + wc * 64 + n * 16 + lr;
#pragma unroll
      for (int r = 0; r < 4; ++r)
        out[(size_t)(rbase + m * 16 + r) * OUT_F + col] = acc[m][n][r] + bv[n];
    }
}

// ---------------------------------------------------------------------------
// fp32 fallback (tiny workspace): exact, slow but correct.
__global__ void lora_t(const float* __restrict__ x, const float* __restrict__ B,
                       float* __restrict__ t) {
  int m = blockIdx.x;
  int tid = threadIdx.x, lane = tid & 63;
  float p[8] = {0, 0, 0, 0, 0, 0, 0, 0};
  for (int k = tid; k < IN_F; k += 256) {
    float xv = x[(size_t)m * IN_F + k];
#pragma unroll
    for (int r = 0; r < 8; ++r) p[r] += xv * B[r * IN_F + k];
  }
#pragma unroll
  for (int r = 0; r < 8; ++r) {
    float v = p[r];
    for (int off = 32; off; off >>= 1) v += __shfl_down(v, off);
    if (lane == 0) atomicAdd(&t[m * 8 + r], v);
  }
}

__global__ void fb_gemm(const float* __restrict__ x, const float* __restrict__ W,
                        const float* __restrict__ A, const float* __restrict__ bias,
                        const float* __restrict__ t, float* __restrict__ out) {
  __shared__ float sx[64][17];
  __shared__ float sw[64][17];
  int tx = threadIdx.x, ty = threadIdx.y;
  int tid = ty * 16 + tx;
  int m0 = blockIdx.y * 64, n0 = blockIdx.x * 64;
  float acc[4][4] = {};
  for (int kt = 0; kt < IN_F; kt += 16) {
    __syncthreads();
#pragma unroll
    for (int q = 0; q < 4; ++q) {
      int idx = q * 256 + tid;
      int r = idx >> 4, c = idx & 15;
      sx[r][c] = x[(size_t)(m0 + r) * IN_F + kt + c];
      sw[r][c] = W[(size_t)(n0 + r) * IN_F + kt + c];
    }
    __syncthreads();
#pragma unroll
    for (int k = 0; k < 16; ++k) {
      float xv[4], wv[4];
#pragma unroll
      for (int i = 0; i < 4; ++i) xv[i] = sx[ty * 4 + i][k];
#pragma unroll
      for (int j = 0; j < 4; ++j) wv[j] = sw[tx * 4 + j][k];
#pragma unroll
      for (int i = 0; i < 4; ++i)
#pragma unroll
        for (int j = 0; j < 4; ++j) acc[i][j] += xv[i] * wv[j];
    }
  }
#pragma unroll
  for (int i = 0; i < 4; ++i) {
    int m = m0 + ty * 4 + i;
    float tv[8];
#pragma unroll
    for (int r = 0; r < 8; ++r) tv[r] = t[m * 8 + r];
#pragma unroll
    for (int j = 0; j < 4; ++j) {
      int o = n0 + tx * 4 + j;
      float lora = 0.f;
#pragma unroll
      for (int r = 0; r < 8; ++r) lora += tv[r] * A[o * 8 + r];
      out[(size_t)m * OUT_F + o] = acc[i][j] + bias[o] + LORA_SCALE * lora;
    }
  }
}

// ---------------------------------------------------------------------------
extern "C" void kernel_launch(void* const* d_in, const int* in_sizes, int n_in,
                              void* d_out, int out_size, void* d_ws, size_t ws_size,
                              hipStream_t stream) {
  const float* x    = (const float*)d_in[0];
  const float* W    = (const float*)d_in[1];
  const float* A    = (const float*)d_in[2];
  const float* B    = (const float*)d_in[3];
  const float* bias = (const float*)d_in[4];
  float* out = (float*)d_out;

  const size_t xb_elems = (size_t)M_TOT * IN_F;
  const size_t wb_elems = (size_t)OUT_F * IN_F;
  const size_t need = (xb_elems + wb_elems) * sizeof(u16);

  if (ws_size >= need) {
    u16* Xb = (u16*)d_ws;
    u16* Wb = Xb + xb_elems;
    merge_weight<<<(OUT_F * IN_F / 4) / 256, 256, 0, stream>>>(W, A, B, Wb);
    convert_x<<<(M_TOT * IN_F / 8) / 256, 256, 0, stream>>>(x, Xb);

    hipError_t e = hipFuncSetAttribute((const void*)gemm8,
                                       hipFuncAttributeMaxDynamicSharedMemorySize,
                                       131072);
    bool used8 = false;
    if (e == hipSuccess) {
      gemm8<<<512, 512, 131072, stream>>>(Xb, Wb, bias, out);
      used8 = (hipGetLastError() == hipSuccess);
    }
    if (!used8) {
      gemm_bias<<<(M_TOT / 128) * (OUT_F / 128), 256, 0, stream>>>(Xb, Wb, bias, out);
    }
  } else {
    float* t = (float*)d_ws;
    hipMemsetAsync(t, 0, (size_t)M_TOT * 8 * sizeof(float), stream);
    lora_t<<<M_TOT, 256, 0, stream>>>(x, B, t);
    fb_gemm<<<dim3(OUT_F / 64, M_TOT / 64), dim3(16, 16), 0, stream>>>(x, W, A, bias, t, out);
  }
}

// Round 4
// 294.728 us; speedup vs baseline: 1.1956x; 1.0169x over previous
//
#include <hip/hip_runtime.h>
#include <stdint.h>

#define IN_F 4096
#define OUT_F 4096
#define M_TOT 8192
#define LORA_SCALE 4.0f   // ALPHA / RANK = 32 / 8

typedef unsigned short u16;
typedef __attribute__((ext_vector_type(8))) short bf16x8;   // 8 bf16 = 4 VGPRs
typedef __attribute__((ext_vector_type(4))) float f32x4;

__device__ __forceinline__ u16 f2bf(float f) {
  union { float f; unsigned u; } v; v.f = f;
  unsigned r = v.u + 0x7FFFu + ((v.u >> 16) & 1u);  // round-to-nearest-even
  return (u16)(r >> 16);
}

__device__ __forceinline__ void gload_lds16(const void* g, void* l) {
  __builtin_amdgcn_global_load_lds(
      (const __attribute__((address_space(1))) void*)g,
      (__attribute__((address_space(3))) void*)l, 16, 0, 0);
}

// ---------------------------------------------------------------------------
// Fused prep: blocks [0, 16384)   : Xb = bf16(x)            (8 elems/thread)
//             blocks [16384, 32768): Wb = bf16(W + 4*a@b)   (4 elems/thread)
// Single-pass inputs use nontemporal loads (don't evict Xb/Wb from L3).
// NOTE: __builtin_nontemporal_load needs ext_vector pointers (f32x4), not
// the HIP_vector_type struct float4.
__global__ void prep(const float* __restrict__ X, const float* __restrict__ W,
                     const float* __restrict__ A, const float* __restrict__ B,
                     u16* __restrict__ Xb, u16* __restrict__ Wb) {
  int bid = blockIdx.x;
  if (bid < 16384) {
    size_t base = ((size_t)bid * blockDim.x + threadIdx.x) * 8;
    const f32x4* p = (const f32x4*)(X + base);
    f32x4 v0 = __builtin_nontemporal_load(p);
    f32x4 v1 = __builtin_nontemporal_load(p + 1);
    uint4 pk;
    pk.x = (unsigned)f2bf(v0.x) | ((unsigned)f2bf(v0.y) << 16);
    pk.y = (unsigned)f2bf(v0.z) | ((unsigned)f2bf(v0.w) << 16);
    pk.z = (unsigned)f2bf(v1.x) | ((unsigned)f2bf(v1.y) << 16);
    pk.w = (unsigned)f2bf(v1.z) | ((unsigned)f2bf(v1.w) << 16);
    *(uint4*)(Xb + base) = pk;
  } else {
    int idx = (bid - 16384) * blockDim.x + threadIdx.x;
    int o  = idx >> 10;
    int i0 = (idx & 1023) << 2;
    const f32x4 w = __builtin_nontemporal_load((const f32x4*)(W + (size_t)o * IN_F + i0));
    float a0 = w.x, a1 = w.y, a2 = w.z, a3 = w.w;
#pragma unroll
    for (int r = 0; r < 8; ++r) {
      float ar = A[o * 8 + r] * LORA_SCALE;
      const float4 bv = *(const float4*)(B + (size_t)r * IN_F + i0);
      a0 += ar * bv.x; a1 += ar * bv.y; a2 += ar * bv.z; a3 += ar * bv.w;
    }
    uint2 pk;
    pk.x = (unsigned)f2bf(a0) | ((unsigned)f2bf(a1) << 16);
    pk.y = (unsigned)f2bf(a2) | ((unsigned)f2bf(a3) << 16);
    *(uint2*)(Wb + (size_t)o * IN_F + i0) = pk;
  }
}

// ---------------------------------------------------------------------------
// GEMM: 256x256 tile, BK=64, 8 waves (2Mx4N), SINGLE-barrier 8-phase schedule
// with counted vmcnt (T3+T4), XOR-swizzled LDS (T2), setprio (T5), XCD (T1).
//
// Phase = { s_barrier; sched_barrier(0); ds_reads; stage 1 half-tile;
//           setprio(1); 16 MFMA; setprio(0) }   (compiler-counted lgkm waits)
// WAIT vmcnt(4) once per K-tile, after ph3's MFMA, before next barrier.
//
// Race-freedom (1-barrier): the only same-buffer overwrite is B[b] staged in
// ph2/ph3 while read in ph0. A wave passing bar(ph2) implies all waves
// finished ph1's MFMA, hence all ph0 LDS reads completed >=1 phase earlier.
// A[b^1] staged in ph0/ph1 was last read in the PREVIOUS tile's ph3, complete
// before any wave passes bar(ph0). sched_barrier(0) after each s_barrier and
// "memory" on the WAIT asm pin compile-time motion to the proven order.

#define ABASE(b) ((b) * 32768)
#define BBASE(b) ((b) * 32768 + 16384)

#define STAGE_A(b, h, kt) do { \
  gload_lds16(aG + (size_t)((h) * 128) * IN_F + (kt),      lds + ABASE(b) + ((h) * 128) * 64      + tid * 8); \
  gload_lds16(aG + (size_t)((h) * 128 + 64) * IN_F + (kt), lds + ABASE(b) + ((h) * 128 + 64) * 64 + tid * 8); \
} while (0)

#define STAGE_B(b, h, kt) do { \
  gload_lds16(bG + (size_t)((h) * 128) * IN_F + (kt),      lds + BBASE(b) + ((h) * 128) * 64      + tid * 8); \
  gload_lds16(bG + (size_t)((h) * 128 + 64) * IN_F + (kt), lds + BBASE(b) + ((h) * 128 + 64) * 64 + tid * 8); \
} while (0)

#define WAIT4 asm volatile("s_waitcnt vmcnt(4)" ::: "memory")
#define WAIT0 asm volatile("s_waitcnt vmcnt(0)" ::: "memory")

#define PHASE(b, p, STAGE_STMT) do { \
  __builtin_amdgcn_s_barrier(); \
  __builtin_amdgcn_sched_barrier(0); \
  if ((p) == 0) { \
    _Pragma("unroll") \
    for (int n = 0; n < 4; ++n) { \
      Bf0[n] = *(const bf16x8*)(lds + BBASE(b) + (rB + n * 16) * 64 + ck0); \
      Bf1[n] = *(const bf16x8*)(lds + BBASE(b) + (rB + n * 16) * 64 + ck1); \
    } \
  } \
  bf16x8 a00 = *(const bf16x8*)(lds + ABASE(b) + (rA + (2 * (p)) * 16) * 64 + ck0); \
  bf16x8 a01 = *(const bf16x8*)(lds + ABASE(b) + (rA + (2 * (p)) * 16) * 64 + ck1); \
  bf16x8 a10 = *(const bf16x8*)(lds + ABASE(b) + (rA + (2 * (p) + 1) * 16) * 64 + ck0); \
  bf16x8 a11 = *(const bf16x8*)(lds + ABASE(b) + (rA + (2 * (p) + 1) * 16) * 64 + ck1); \
  STAGE_STMT; \
  __builtin_amdgcn_s_setprio(1); \
  _Pragma("unroll") \
  for (int n = 0; n < 4; ++n) { \
    acc[2 * (p)][n]     = __builtin_amdgcn_mfma_f32_16x16x32_bf16(a00, Bf0[n], acc[2 * (p)][n], 0, 0, 0); \
    acc[2 * (p) + 1][n] = __builtin_amdgcn_mfma_f32_16x16x32_bf16(a10, Bf0[n], acc[2 * (p) + 1][n], 0, 0, 0); \
  } \
  _Pragma("unroll") \
  for (int n = 0; n < 4; ++n) { \
    acc[2 * (p)][n]     = __builtin_amdgcn_mfma_f32_16x16x32_bf16(a01, Bf1[n], acc[2 * (p)][n], 0, 0, 0); \
    acc[2 * (p) + 1][n] = __builtin_amdgcn_mfma_f32_16x16x32_bf16(a11, Bf1[n], acc[2 * (p) + 1][n], 0, 0, 0); \
  } \
  __builtin_amdgcn_s_setprio(0); \
} while (0)

__global__ __launch_bounds__(512, 2) void gemm8(const u16* __restrict__ Xb,
                                                const u16* __restrict__ Wb,
                                                const float* __restrict__ bias,
                                                float* __restrict__ out) {
  extern __shared__ u16 lds[];

  const int tid  = threadIdx.x;
  const int lane = tid & 63;
  const int wid  = tid >> 6;
  const int wr = wid >> 2, wc = wid & 3;       // 2x4 waves, 128x64 C each
  const int lr = lane & 15, kg = lane >> 4;

  // XCD-aware swizzle: nwg = 512, divisible by 8
  const int bid = blockIdx.x;
  const int swz = (bid & 7) * 64 + (bid >> 3);
  const int mt = swz >> 4, nt = swz & 15;       // 32 M-tiles x 16 N-tiles
  const int m0 = mt * 256, n0 = nt * 256;

  // staging: per half-tile (128 rows x 64 bf16), 2 gloads/thread.
  // LDS dest linear (lane*16); global source pre-swizzled chunk^(row&7).
  const int srow = tid >> 3;                                  // 0..63
  const int swc  = (tid & 7) ^ (srow & 7);
  const u16* aG = Xb + (size_t)(m0 + srow) * IN_F + swc * 8;
  const u16* bG = Wb + (size_t)(n0 + srow) * IN_F + swc * 8;

  // fragment read offsets (swizzled)
  const int rA = wr * 128 + lr;
  const int rB = wc * 64 + lr;
  const int ck0 = ((kg) ^ (lane & 7)) * 8;       // k-slice 0
  const int ck1 = ((4 + kg) ^ (lane & 7)) * 8;   // k-slice 1

  f32x4 acc[8][4] = {};
  bf16x8 Bf0[4], Bf1[4];

  // prologue: tile0.{B,A}, tile1.B staged; wait tile0 landed (tile1.B in flight)
  STAGE_B(0, 0, 0); STAGE_B(0, 1, 0);
  STAGE_A(0, 0, 0); STAGE_A(0, 1, 0);
  STAGE_B(1, 0, 64); STAGE_B(1, 1, 64);
  WAIT4;

  for (int i = 0; i < 31; ++i) {
    const int kt1 = i * 128 + 64, kt2 = i * 128 + 128, kt3 = i * 128 + 192;
    // tile 2i (buffer 0)
    PHASE(0, 0, STAGE_A(1, 0, kt1));
    PHASE(0, 1, STAGE_A(1, 1, kt1));
    PHASE(0, 2, STAGE_B(0, 0, kt2));
    PHASE(0, 3, STAGE_B(0, 1, kt2));
    WAIT4;
    // tile 2i+1 (buffer 1)
    PHASE(1, 0, STAGE_A(0, 0, kt2));
    PHASE(1, 1, STAGE_A(0, 1, kt2));
    PHASE(1, 2, STAGE_B(1, 0, kt3));
    PHASE(1, 3, STAGE_B(1, 1, kt3));
    WAIT4;
  }
  // tile 62 (buf 0): stage A for tile 63 only, then drain
  PHASE(0, 0, STAGE_A(1, 0, 4032));
  PHASE(0, 1, STAGE_A(1, 1, 4032));
  PHASE(0, 2, );
  PHASE(0, 3, );
  WAIT0;
  // tile 63 (buf 1): pure compute
  PHASE(1, 0, );
  PHASE(1, 1, );
  PHASE(1, 2, );
  PHASE(1, 3, );

  // C write + bias (nontemporal: out is never re-read; keep L3 for Xb/Wb).
  // C/D layout: col = lane&15, row = (lane>>4)*4 + reg
  float bv[4];
#pragma unroll
  for (int n = 0; n < 4; ++n) bv[n] = bias[n0 + wc * 64 + n * 16 + lr];
  const int rbase = m0 + wr * 128 + kg * 4;
#pragma unroll
  for (int m = 0; m < 8; ++m)
#pragma unroll
    for (int n = 0; n < 4; ++n) {
      int col = n0 + wc * 64 + n * 16 + lr;
#pragma unroll
      for (int r = 0; r < 4; ++r)
        __builtin_nontemporal_store(acc[m][n][r] + bv[n],
                                    &out[(size_t)(rbase + m * 16 + r) * OUT_F + col]);
    }
}

// ---------------------------------------------------------------------------
// Fallback GEMM (proven round-1 kernel): 128x128 tile, m97 structure, 859 TF.
__global__ __launch_bounds__(256) void gemm_bias(const u16* __restrict__ Xb,
                                                 const u16* __restrict__ Wb,
                                                 const float* __restrict__ bias,
                                                 float* __restrict__ out) {
  __shared__ __align__(16) u16 ldsA[128 * 64];
  __shared__ __align__(16) u16 ldsB[128 * 64];

  const int tid  = threadIdx.x;
  const int wid  = tid >> 6;
  const int lane = tid & 63;
  const int nt = blockIdx.x & 31;
  const int mt = blockIdx.x >> 5;
  const int m0 = mt * 128, n0 = nt * 128;
  const int wr = wid >> 1, wc = wid & 1;
  const int lr = lane & 15;
  const int kg = lane >> 4;

  const int srow   = wid * 8 + (lane >> 3);
  const int schunk = (lane & 7) ^ (srow & 7);
  const u16* aSrc = Xb + (size_t)(m0 + srow) * IN_F + schunk * 8;
  const u16* bSrc = Wb + (size_t)(n0 + srow) * IN_F + schunk * 8;

  f32x4 acc[4][4] = {};

  for (int kt = 0; kt < IN_F; kt += 64) {
    __syncthreads();
#pragma unroll
    for (int j = 0; j < 4; ++j) {
      gload_lds16(aSrc + (size_t)(j * 32) * IN_F + kt, &ldsA[j * 2048 + wid * 512]);
      gload_lds16(bSrc + (size_t)(j * 32) * IN_F + kt, &ldsB[j * 2048 + wid * 512]);
    }
    __syncthreads();

#pragma unroll
    for (int s = 0; s < 2; ++s) {
      bf16x8 af[4], bfr[4];
#pragma unroll
      for (int m = 0; m < 4; ++m) {
        int r = wr * 64 + m * 16 + lr;
        int c = (s * 4 + kg) ^ (r & 7);
        af[m] = *(const bf16x8*)&ldsA[r * 64 + c * 8];
      }
#pragma unroll
      for (int n = 0; n < 4; ++n) {
        int r = wc * 64 + n * 16 + lr;
        int c = (s * 4 + kg) ^ (r & 7);
        bfr[n] = *(const bf16x8*)&ldsB[r * 64 + c * 8];
      }
#pragma unroll
      for (int m = 0; m < 4; ++m)
#pragma unroll
        for (int n = 0; n < 4; ++n)
          acc[m][n] = __builtin_amdgcn_mfma_f32_16x16x32_bf16(af[m], bfr[n], acc[m][n], 0, 0, 0);
    }
  }

  float bv[4];
#pragma unroll
  for (int n = 0; n < 4; ++n) bv[n] = bias[n0 + wc * 64 + n * 16 + lr];
  const int rbase = m0 + wr * 64 + kg * 4;
#pragma unroll
  for (int m = 0; m < 4; ++m)
#pragma unroll
    for (int n = 0; n < 4; ++n) {
      int col = n0 + wc * 64 + n * 16 + lr;
#pragma unroll
      for (int r = 0; r < 4; ++r)
        out[(size_t)(rbase + m * 16 + r) * OUT_F + col] = acc[m][n][r] + bv[n];
    }
}

// ---------------------------------------------------------------------------
// fp32 fallback (tiny workspace): exact, slow but correct.
__global__ void lora_t(const float* __restrict__ x, const float* __restrict__ B,
                       float* __restrict__ t) {
  int m = blockIdx.x;
  int tid = threadIdx.x, lane = tid & 63;
  float p[8] = {0, 0, 0, 0, 0, 0, 0, 0};
  for (int k = tid; k < IN_F; k += 256) {
    float xv = x[(size_t)m * IN_F + k];
#pragma unroll
    for (int r = 0; r < 8; ++r) p[r] += xv * B[r * IN_F + k];
  }
#pragma unroll
  for (int r = 0; r < 8; ++r) {
    float v = p[r];
    for (int off = 32; off; off >>= 1) v += __shfl_down(v, off);
    if (lane == 0) atomicAdd(&t[m * 8 + r], v);
  }
}

__global__ void fb_gemm(const float* __restrict__ x, const float* __restrict__ W,
                        const float* __restrict__ A, const float* __restrict__ bias,
                        const float* __restrict__ t, float* __restrict__ out) {
  __shared__ float sx[64][17];
  __shared__ float sw[64][17];
  int tx = threadIdx.x, ty = threadIdx.y;
  int tid = ty * 16 + tx;
  int m0 = blockIdx.y * 64, n0 = blockIdx.x * 64;
  float acc[4][4] = {};
  for (int kt = 0; kt < IN_F; kt += 16) {
    __syncthreads();
#pragma unroll
    for (int q = 0; q < 4; ++q) {
      int idx = q * 256 + tid;
      int r = idx >> 4, c = idx & 15;
      sx[r][c] = x[(size_t)(m0 + r) * IN_F + kt + c];
      sw[r][c] = W[(size_t)(n0 + r) * IN_F + kt + c];
    }
    __syncthreads();
#pragma unroll
    for (int k = 0; k < 16; ++k) {
      float xv[4], wv[4];
#pragma unroll
      for (int i = 0; i < 4; ++i) xv[i] = sx[ty * 4 + i][k];
#pragma unroll
      for (int j = 0; j < 4; ++j) wv[j] = sw[tx * 4 + j][k];
#pragma unroll
      for (int i = 0; i < 4; ++i)
#pragma unroll
        for (int j = 0; j < 4; ++j) acc[i][j] += xv[i] * wv[j];
    }
  }
#pragma unroll
  for (int i = 0; i < 4; ++i) {
    int m = m0 + ty * 4 + i;
    float tv[8];
#pragma unroll
    for (int r = 0; r < 8; ++r) tv[r] = t[m * 8 + r];
#pragma unroll
    for (int j = 0; j < 4; ++j) {
      int o = n0 + tx * 4 + j;
      float lora = 0.f;
#pragma unroll
      for (int r = 0; r < 8; ++r) lora += tv[r] * A[o * 8 + r];
      out[(size_t)m * OUT_F + o] = acc[i][j] + bias[o] + LORA_SCALE * lora;
    }
  }
}

// ---------------------------------------------------------------------------
extern "C" void kernel_launch(void* const* d_in, const int* in_sizes, int n_in,
                              void* d_out, int out_size, void* d_ws, size_t ws_size,
                              hipStream_t stream) {
  const float* x    = (const float*)d_in[0];
  const float* W    = (const float*)d_in[1];
  const float* A    = (const float*)d_in[2];
  const float* B    = (const float*)d_in[3];
  const float* bias = (const float*)d_in[4];
  float* out = (float*)d_out;

  const size_t xb_elems = (size_t)M_TOT * IN_F;
  const size_t wb_elems = (size_t)OUT_F * IN_F;
  const size_t need = (xb_elems + wb_elems) * sizeof(u16);

  if (ws_size >= need) {
    u16* Xb = (u16*)d_ws;
    u16* Wb = Xb + xb_elems;
    prep<<<32768, 256, 0, stream>>>(x, W, A, B, Xb, Wb);

    hipError_t e = hipFuncSetAttribute((const void*)gemm8,
                                       hipFuncAttributeMaxDynamicSharedMemorySize,
                                       131072);
    bool used8 = false;
    if (e == hipSuccess) {
      gemm8<<<512, 512, 131072, stream>>>(Xb, Wb, bias, out);
      used8 = (hipGetLastError() == hipSuccess);
    }
    if (!used8) {
      gemm_bias<<<(M_TOT / 128) * (OUT_F / 128), 256, 0, stream>>>(Xb, Wb, bias, out);
    }
  } else {
    float* t = (float*)d_ws;
    (void)hipMemsetAsync(t, 0, (size_t)M_TOT * 8 * sizeof(float), stream);
    lora_t<<<M_TOT, 256, 0, stream>>>(x, B, t);
    fb_gemm<<<dim3(OUT_F / 64, M_TOT / 64), dim3(16, 16), 0, stream>>>(x, W, A, bias, t, out);
  }
}